// Round 17
// baseline (1021.074 us; speedup 1.0000x reference)
//
#include <hip/hip_runtime.h>
#include <hip/hip_bf16.h>
#include <stdint.h>

#define D_ 128
#define R_ 200
#define B_ 50
#define N_ 100000
#define TE 64
#define RG_ 4
#define MAXC 8
#define NBMAX (MAXC * R_)
#define SUBS 8

typedef __attribute__((ext_vector_type(8))) short s8b;
typedef __attribute__((ext_vector_type(4))) float f32x4;
typedef __attribute__((ext_vector_type(4))) uint u32x4;

// ---------------- helpers ----------------

__device__ __forceinline__ ushort f2bf(float f) {   // RTN-even fp32 -> bf16
  uint u = __float_as_uint(f);
  return (ushort)((u + 0x7fffu + ((u >> 16) & 1u)) >> 16);
}
__device__ __forceinline__ float bf2f(ushort u) {
  return __uint_as_float(((uint)u) << 16);
}

// ---------------- bucket histogram: bucket = (dst/DCH)*R + rel ----------------

__global__ __launch_bounds__(256) void k_hist(const int* __restrict__ dst, const int* __restrict__ et,
                                              int E, int* __restrict__ hist, int DCH, int NB) {
  __shared__ int h[NBMAX];
  for (int i = threadIdx.x; i < NB; i += 256) h[i] = 0;
  __syncthreads();
  int base = blockIdx.x * 2048;
  for (int j = 0; j < 8; j++) {
    int i = base + j * 256 + threadIdx.x;
    if (i < E) {
      int key = (dst[i] / DCH) * R_ + et[i];
      atomicAdd(&h[key], 1);
    }
  }
  __syncthreads();
  for (int i = threadIdx.x; i < NB; i += 256) { int v = h[i]; if (v) atomicAdd(&hist[i], v); }
}

// parallel bucket scan with TE-padding (1 block, 1024 threads, 2 buckets/thread)
__global__ __launch_bounds__(1024) void k_scanRel(const int* __restrict__ hist,
                                                  int* __restrict__ padOff, int* __restrict__ cursor, int NB) {
  __shared__ int s[1024];
  int tid = threadIdx.x;
  int i0 = 2 * tid, i1 = 2 * tid + 1;
  int v0 = (i0 < NB) ? ((hist[i0] + TE - 1) / TE) * TE : 0;
  int v1 = (i1 < NB) ? ((hist[i1] + TE - 1) / TE) * TE : 0;
  int v = v0 + v1;
  s[tid] = v;
  __syncthreads();
  for (int off = 1; off < 1024; off <<= 1) {
    int t = (tid >= off) ? s[tid - off] : 0;
    __syncthreads();
    s[tid] += t;
    __syncthreads();
  }
  int e = s[tid] - v;
  if (i0 < NB) { padOff[i0] = e; cursor[i0] = e; }
  if (i1 < NB) { padOff[i1] = e + v0; cursor[i1] = e + v0; }
  if (tid == 1023) padOff[NB] = s[1023];
}

// bucket-sort scatter + per-(dst,sub) rank; sub-counters in SEPARATE LINES (cnt[sub*N_+d])
__global__ __launch_bounds__(256) void k_scatter(const int* __restrict__ src, const int* __restrict__ dst,
                                                 const int* __restrict__ et, int E,
                                                 int* __restrict__ cursor,
                                                 uint2* __restrict__ sd2, int* __restrict__ cnt,
                                                 int DCH, int NB) {
  __shared__ int h[NBMAX];
  __shared__ int gb[NBMAX];
  for (int i = threadIdx.x; i < NB; i += 256) h[i] = 0;
  __syncthreads();
  int base = blockIdx.x * 2048;
  int lrank[8];
#pragma unroll
  for (int j = 0; j < 8; j++) {
    int i = base + j * 256 + threadIdx.x;
    lrank[j] = 0;
    if (i < E) {
      int key = (dst[i] / DCH) * R_ + et[i];
      lrank[j] = atomicAdd(&h[key], 1);
    }
  }
  __syncthreads();
  for (int i = threadIdx.x; i < NB; i += 256) { int v = h[i]; gb[i] = v ? atomicAdd(&cursor[i], v) : 0; }
  __syncthreads();
#pragma unroll
  for (int j = 0; j < 8; j++) {
    int i = base + j * 256 + threadIdx.x;
    if (i < E) {
      int d = dst[i];
      int key = (d / DCH) * R_ + et[i];
      int pos = gb[key] + lrank[j];
      int sub = i & (SUBS - 1);
      int rank = atomicAdd(&cnt[sub * N_ + d], 1);
      uint2 sd;
      sd.x = (uint)src[i];
      sd.y = (uint)d | ((uint)sub << 17) | ((uint)rank << 20);
      sd2[pos] = sd;
    }
  }
}

__global__ __launch_bounds__(256) void k_tileRel(const int* __restrict__ padOff, int* __restrict__ tileRel,
                                                 int uT, int NB) {
  int t = blockIdx.x * 256 + threadIdx.x;
  if (t >= uT) return;
  int base = t * TE;
  if (base >= padOff[NB]) { tileRel[t] = 0; return; }
  int lo = 0, hi = NB - 1;
  while (lo < hi) { int mid = (lo + hi + 1) >> 1; if (padOff[mid] <= base) lo = mid; else hi = mid - 1; }
  tileRel[t] = lo % R_;
}

// cnt -> in-place exclusive sub-prefixes; deg[d] = total
__global__ __launch_bounds__(256) void k_sub(int* __restrict__ cnt, int* __restrict__ deg) {
  int d = blockIdx.x * 256 + threadIdx.x;
  if (d >= N_) return;
  int run = 0;
#pragma unroll
  for (int s = 0; s < SUBS; ++s) {
    int v = cnt[s * N_ + d];
    cnt[s * N_ + d] = run;
    run += v;
  }
  deg[d] = run;
}

// ---------------- dst offsets ----------------

__global__ __launch_bounds__(256) void k_degPart(const int* __restrict__ deg, int* __restrict__ blkSum) {
  __shared__ int ws_[4];
  int i = blockIdx.x * 256 + threadIdx.x;
  int v = (i < N_) ? deg[i] : 0;
#pragma unroll
  for (int off = 32; off >= 1; off >>= 1) v += __shfl_down(v, off);
  if ((threadIdx.x & 63) == 0) ws_[threadIdx.x >> 6] = v;
  __syncthreads();
  if (threadIdx.x == 0) blkSum[blockIdx.x] = ws_[0] + ws_[1] + ws_[2] + ws_[3];
}

__global__ __launch_bounds__(512) void k_scanBlk(const int* __restrict__ blkSum, int* __restrict__ blkOff, int nblk) {
  __shared__ int s[512];
  int tid = threadIdx.x;
  int v = (tid < nblk) ? blkSum[tid] : 0;
  s[tid] = v;
  __syncthreads();
  for (int off = 1; off < 512; off <<= 1) {
    int t = (tid >= off) ? s[tid - off] : 0;
    __syncthreads();
    s[tid] += t;
    __syncthreads();
  }
  if (tid < nblk) blkOff[tid] = s[tid] - v;
}

__global__ __launch_bounds__(256) void k_writeOff(const int* __restrict__ deg, const int* __restrict__ blkOff,
                                                  int* __restrict__ dstOff) {
  __shared__ int s[256];
  int i = blockIdx.x * 256 + threadIdx.x;
  int tid = threadIdx.x;
  int v = (i < N_) ? deg[i] : 0;
  s[tid] = v;
  __syncthreads();
  for (int off = 1; off < 256; off <<= 1) {
    int t = (tid >= off) ? s[tid - off] : 0;
    __syncthreads();
    s[tid] += t;
    __syncthreads();
  }
  int e = blkOff[blockIdx.x] + s[tid] - v;
  if (i < N_) dstOff[i] = e;
  else if (i == N_) dstOff[N_] = e;
}

// non-atomic posbuf build (fields unpacked from sd2.y)
__global__ __launch_bounds__(256) void k_buildPos(const uint2* __restrict__ sd2, const int* __restrict__ dstOff,
                                                  const int* __restrict__ cnt, int* __restrict__ posbuf, int pTot) {
  int p = blockIdx.x * 256 + threadIdx.x;
  if (p >= pTot) return;
  uint y = sd2[p].y;
  if (y == 0xFFFFFFFFu) return;      // padding slot
  int d = (int)(y & 0x1FFFFu);
  int sub = (int)((y >> 17) & 7u);
  int rank = (int)(y >> 20);
  posbuf[dstOff[d] + cnt[sub * N_ + d] + rank] = p;
}

// ---------------- per-edge mean-norm from dst-sorted segments ----------------

__global__ __launch_bounds__(256) void k_norm(const int* __restrict__ posbuf, const int* __restrict__ dstOff,
                                              const int* __restrict__ tileRel, float* __restrict__ normS) {
  __shared__ int rels[4][128];
  int d = blockIdx.x * 4 + (threadIdx.x >> 6);
  int sub = threadIdx.x >> 6;
  int l = threadIdx.x & 63;
  int s0 = 0, deg = 0;
  if (d < N_) { s0 = dstOff[d]; deg = dstOff[d + 1] - s0; }
  int cap = deg < 128 ? deg : 128;
  int myp[4]; int myr[4];
  for (int j = l, t = 0; j < cap; j += 64, ++t) {
    int p = posbuf[s0 + j];
    int r = tileRel[p >> 6];
    rels[sub][j] = r;
    if (t < 4) { myp[t] = p; myr[t] = r; }
  }
  __syncthreads();
  if (d >= N_) return;
  for (int j = l, t = 0; j < deg; j += 64, ++t) {
    int p, r;
    if (j < 128 && t < 4) { p = myp[t]; r = myr[t]; }
    else { p = posbuf[s0 + j]; r = tileRel[p >> 6]; }
    int cnt = 0;
    for (int k = 0; k < deg; k++) {
      int rk = (k < 128) ? rels[sub][k] : tileRel[posbuf[s0 + k] >> 6];
      cnt += (rk == r) ? 1 : 0;
    }
    normS[p] = 1.0f / (float)(cnt > 0 ? cnt : 1);
  }
}

// ---------------- W_r = sum_b comp[r,b]*basis[b]; pack to B-fragment order ----------------

__global__ __launch_bounds__(256) void k_computeW(const float* __restrict__ comp, const float* __restrict__ basis,
                                                  float* __restrict__ W) {
  __shared__ float c[B_];
  int r = blockIdx.x >> 6;
  int chunk = blockIdx.x & 63;
  if (threadIdx.x < B_) c[threadIdx.x] = comp[r * B_ + threadIdx.x];
  __syncthreads();
  int ij = chunk * 256 + threadIdx.x;
  float acc = 0.f;
#pragma unroll 10
  for (int b = 0; b < B_; b++) acc += c[b] * basis[b * (D_ * D_) + ij];
  W[r * (D_ * D_) + ij] = acc;
}

__global__ __launch_bounds__(256) void k_packW(const float* __restrict__ W, ushort* __restrict__ Wpack) {
  int r = blockIdx.x;
  const float* Wr = W + (size_t)r * (D_ * D_);
  ushort* out = Wpack + (size_t)r * (D_ * D_);
  for (int i = threadIdx.x; i < D_ * D_; i += 256) {
    int j = i & 7, l = (i >> 3) & 63, cg = (i >> 9) & 7, ks = i >> 12;
    int k = ks * 32 + (l >> 4) * 8 + j;
    int n = cg * 16 + (l & 15);
    out[i] = f2bf(Wr[k * D_ + n]);
  }
}

__global__ __launch_bounds__(256) void k_cast(const float* __restrict__ x, ushort* __restrict__ xb, int n8) {
  int i = blockIdx.x * 256 + threadIdx.x;
  if (i >= n8) return;
  const float4* xp = (const float4*)(x + (size_t)i * 8);
  float4 a = xp[0], b = xp[1];
  uint4 pk;
  pk.x = (uint)f2bf(a.x) | ((uint)f2bf(a.y) << 16);
  pk.y = (uint)f2bf(a.z) | ((uint)f2bf(a.w) << 16);
  pk.z = (uint)f2bf(b.x) | ((uint)f2bf(b.y) << 16);
  pk.w = (uint)f2bf(b.z) | ((uint)f2bf(b.w) << 16);
  *(uint4*)(xb + (size_t)i * 8) = pk;
}

// ---------------- y = x @ root + bias (MFMA, LDS-resident W, full-line stores) ----------------

__global__ __launch_bounds__(256, 2) void k_root_mfma(
    const ushort* __restrict__ xb, const ushort* __restrict__ rootPack,
    const float* __restrict__ bias, float* __restrict__ y, int nt) {
  __shared__ ushort Wl[D_ * D_];
  __shared__ float stg[4][16 * 132];
  int tstart = blockIdx.x * RG_;
  if (tstart >= nt) return;
  int tend = tstart + RG_; if (tend > nt) tend = nt;
  int w = threadIdx.x >> 6, l = threadIdx.x & 63;
  int q = l >> 4, tx = l & 15;
  int half = l >> 5, l32 = l & 31;
  float* st = stg[w];
  {
    const uint4* wp = (const uint4*)rootPack;
    uint4* wl = (uint4*)Wl;
#pragma unroll
    for (int i = 0; i < 8; ++i) wl[i * 256 + threadIdx.x] = wp[i * 256 + threadIdx.x];
  }
  float bv[8];
#pragma unroll
  for (int cg = 0; cg < 8; ++cg) bv[cg] = bias[cg * 16 + tx];
  s8b a0, a1, a2, a3;
  {
    int gr = tstart * TE + 16 * w + tx; if (gr >= N_) gr = N_ - 1;
    const s8b* xr = (const s8b*)(xb + (size_t)gr * D_);
    a0 = xr[q]; a1 = xr[4 + q]; a2 = xr[8 + q]; a3 = xr[12 + q];
  }
  __syncthreads();
  for (int tile = tstart; tile < tend; ++tile) {
    int base = tile * TE;
    s8b n0, n1, n2, n3;
    bool pre = (tile + 1 < tend);
    if (pre) {
      int gr = base + TE + 16 * w + tx; if (gr >= N_) gr = N_ - 1;
      const s8b* xn = (const s8b*)(xb + (size_t)gr * D_);
      n0 = xn[q]; n1 = xn[4 + q]; n2 = xn[8 + q]; n3 = xn[12 + q];
    }
    f32x4 acc[8];
#pragma unroll
    for (int cg = 0; cg < 8; ++cg) acc[cg] = (f32x4){0.f, 0.f, 0.f, 0.f};
#pragma unroll
    for (int cg = 0; cg < 8; ++cg) {
      s8b b0 = *(const s8b*)&Wl[((0 * 8 + cg) * 64 + l) * 8];
      s8b b1 = *(const s8b*)&Wl[((1 * 8 + cg) * 64 + l) * 8];
      s8b b2 = *(const s8b*)&Wl[((2 * 8 + cg) * 64 + l) * 8];
      s8b b3 = *(const s8b*)&Wl[((3 * 8 + cg) * 64 + l) * 8];
      acc[cg] = __builtin_amdgcn_mfma_f32_16x16x32_bf16(a0, b0, acc[cg], 0, 0, 0);
      acc[cg] = __builtin_amdgcn_mfma_f32_16x16x32_bf16(a1, b1, acc[cg], 0, 0, 0);
      acc[cg] = __builtin_amdgcn_mfma_f32_16x16x32_bf16(a2, b2, acc[cg], 0, 0, 0);
      acc[cg] = __builtin_amdgcn_mfma_f32_16x16x32_bf16(a3, b3, acc[cg], 0, 0, 0);
    }
#pragma unroll
    for (int cg = 0; cg < 8; ++cg)
#pragma unroll
      for (int r = 0; r < 4; ++r)
        st[(4 * q + r) * 132 + cg * 16 + tx] = acc[cg][r] + bv[cg];
    int grBase = base + 16 * w;
#pragma unroll
    for (int k = 0; k < 8; ++k) {
      int row = 2 * k + half;
      int gr = grBase + row;
      f32x4 v = *(const f32x4*)&st[row * 132 + l32 * 4];
      if (gr < N_) *(f32x4*)(y + (size_t)gr * D_ + l32 * 4) = v;
    }
    if (pre) { a0 = n0; a1 = n1; a2 = n2; a3 = n3; }
  }
}

// ---------------- phase A: MFMA edge messages (dst-range chunk c) ----------------

__global__ __launch_bounds__(256, 4) void k_edges_mfma(
    const ushort* __restrict__ xb, const ushort* __restrict__ Wpack,
    const uint2* __restrict__ sd2, const float* __restrict__ normS,
    const int* __restrict__ tileRel, const int* __restrict__ padOff,
    ushort* __restrict__ msg, int c) {
  __shared__ ushort Wl[D_ * D_];
  __shared__ ushort stg[4][16 * 136];
  int b0 = padOff[c * R_], b1 = padOff[(c + 1) * R_];
  int tile0 = b0 >> 6, tile1 = b1 >> 6;
  int tiles = tile1 - tile0;
  if (tiles <= 0) return;
  int G = (tiles + (int)gridDim.x - 1) / (int)gridDim.x;
  int w = threadIdx.x >> 6, l = threadIdx.x & 63;
  int q = l >> 4, tx = l & 15;
  int g = l >> 3, m = l & 7;
  ushort* st = stg[w];
  int curRel = -1;
  for (int tb = tile0 + blockIdx.x * G; tb < tile1; tb += (int)gridDim.x * G) {
    int tend = tb + G; if (tend > tile1) tend = tile1;
    s8b a0, a1, a2, a3;
    {
      int sr = (int)sd2[tb * TE + 16 * w + tx].x;
      if (sr < 0) sr = 0;
      const s8b* xr = (const s8b*)(xb + (size_t)sr * D_);
      a0 = xr[q]; a1 = xr[4 + q]; a2 = xr[8 + q]; a3 = xr[12 + q];
    }
    for (int tile = tb; tile < tend; ++tile) {
      int base = tile * TE;
      int rel = tileRel[tile];
      if (rel != curRel) {                    // block-uniform branch
        curRel = rel;
        __syncthreads();
        const uint4* wp = (const uint4*)(Wpack + (size_t)rel * (D_ * D_));
        uint4* wl = (uint4*)Wl;
#pragma unroll
        for (int i = 0; i < 8; ++i) wl[i * 256 + threadIdx.x] = wp[i * 256 + threadIdx.x];
        __syncthreads();
      }
      float nv[4];
#pragma unroll
      for (int r = 0; r < 4; ++r) nv[r] = normS[base + 16 * w + 4 * q + r];
      s8b n0, n1, n2, n3;
      bool pre = (tile + 1 < tend);
      if (pre) {
        int sr = (int)sd2[base + TE + 16 * w + tx].x;
        if (sr < 0) sr = 0;
        const s8b* xn = (const s8b*)(xb + (size_t)sr * D_);
        n0 = xn[q]; n1 = xn[4 + q]; n2 = xn[8 + q]; n3 = xn[12 + q];
      }
      f32x4 acc[8];
#pragma unroll
      for (int cg = 0; cg < 8; ++cg) acc[cg] = (f32x4){0.f, 0.f, 0.f, 0.f};
#pragma unroll
      for (int cg = 0; cg < 8; ++cg) {
        s8b b0v = *(const s8b*)&Wl[((0 * 8 + cg) * 64 + l) * 8];
        s8b b1v = *(const s8b*)&Wl[((1 * 8 + cg) * 64 + l) * 8];
        s8b b2v = *(const s8b*)&Wl[((2 * 8 + cg) * 64 + l) * 8];
        s8b b3v = *(const s8b*)&Wl[((3 * 8 + cg) * 64 + l) * 8];
        acc[cg] = __builtin_amdgcn_mfma_f32_16x16x32_bf16(a0, b0v, acc[cg], 0, 0, 0);
        acc[cg] = __builtin_amdgcn_mfma_f32_16x16x32_bf16(a1, b1v, acc[cg], 0, 0, 0);
        acc[cg] = __builtin_amdgcn_mfma_f32_16x16x32_bf16(a2, b2v, acc[cg], 0, 0, 0);
        acc[cg] = __builtin_amdgcn_mfma_f32_16x16x32_bf16(a3, b3v, acc[cg], 0, 0, 0);
      }
#pragma unroll
      for (int cg = 0; cg < 8; ++cg)
#pragma unroll
        for (int r = 0; r < 4; ++r)
          st[(4 * q + r) * 136 + cg * 16 + tx] = f2bf(acc[cg][r] * nv[r]);
      ushort* mbase = msg + (size_t)(base - b0 + 16 * w) * D_;
#pragma unroll
      for (int jj = 0; jj < 2; ++jj)
#pragma unroll
        for (int hh = 0; hh < 2; ++hh) {
          int row = 8 * jj + g;
          u32x4 v = *(const u32x4*)&st[row * 136 + hh * 64 + m * 8];
          *(u32x4*)(mbase + (size_t)row * D_ + hh * 64 + m * 8) = v;
        }
      if (pre) { a0 = n0; a1 = n1; a2 = n2; a3 = n3; }
    }
  }
}

// ---------------- phase B: wave-per-dst aggregation (single touch per dst) ----------------
// mode 1: relu, write fp32 y.  mode 2: relu, write bf16 xbOut (no y write).

__global__ __launch_bounds__(256) void k_agg2(const ushort* __restrict__ msg, const int* __restrict__ posbuf,
                                              const int* __restrict__ dstOff, const int* __restrict__ padOff,
                                              float* __restrict__ y, ushort* __restrict__ xbOut,
                                              int c, int dlo, int dhi, int mode) {
  int d = dlo + blockIdx.x * 4 + (threadIdx.x >> 6);
  if (d >= dhi) return;
  int plo = padOff[c * R_];
  int l = threadIdx.x & 63, sub = l >> 4, tx = l & 15;
  int s0 = dstOff[d], s1 = dstOff[d + 1];
  float acc[8];
#pragma unroll
  for (int i = 0; i < 8; ++i) acc[i] = 0.f;
  for (int j = s0 + sub; j < s1; j += 4) {
    int p = posbuf[j];
    u32x4 mv = *(const u32x4*)(msg + (((size_t)(p - plo)) << 7) + (tx << 3));
    acc[0] += bf2f((ushort)mv[0]); acc[1] += bf2f((ushort)(mv[0] >> 16));
    acc[2] += bf2f((ushort)mv[1]); acc[3] += bf2f((ushort)(mv[1] >> 16));
    acc[4] += bf2f((ushort)mv[2]); acc[5] += bf2f((ushort)(mv[2] >> 16));
    acc[6] += bf2f((ushort)mv[3]); acc[7] += bf2f((ushort)(mv[3] >> 16));
  }
#pragma unroll
  for (int i = 0; i < 8; ++i) {
    acc[i] += __shfl_xor(acc[i], 16);
    acc[i] += __shfl_xor(acc[i], 32);
  }
  if (sub == 0) {
    float* yp = y + (((size_t)d) << 7) + (tx << 3);
    float4 y0 = *(float4*)yp, y1 = *(float4*)(yp + 4);
    y0.x = fmaxf(y0.x + acc[0], 0.f); y0.y = fmaxf(y0.y + acc[1], 0.f);
    y0.z = fmaxf(y0.z + acc[2], 0.f); y0.w = fmaxf(y0.w + acc[3], 0.f);
    y1.x = fmaxf(y1.x + acc[4], 0.f); y1.y = fmaxf(y1.y + acc[5], 0.f);
    y1.z = fmaxf(y1.z + acc[6], 0.f); y1.w = fmaxf(y1.w + acc[7], 0.f);
    if (mode == 1) {
      *(float4*)yp = y0; *(float4*)(yp + 4) = y1;
    } else {
      uint4 pk;
      pk.x = (uint)f2bf(y0.x) | ((uint)f2bf(y0.y) << 16);
      pk.y = (uint)f2bf(y0.z) | ((uint)f2bf(y0.w) << 16);
      pk.z = (uint)f2bf(y1.x) | ((uint)f2bf(y1.y) << 16);
      pk.w = (uint)f2bf(y1.z) | ((uint)f2bf(y1.w) << 16);
      *(uint4*)(xbOut + (((size_t)d) << 7) + (tx << 3)) = pk;
    }
  }
}

// ---------------- launch ----------------

extern "C" void kernel_launch(void* const* d_in, const int* in_sizes, int n_in,
                              void* d_out, int out_size, void* d_ws, size_t ws_size,
                              hipStream_t stream) {
  const float* entity = (const float*)d_in[0];
  const float* comp   = (const float*)d_in[1];
  const float* basis  = (const float*)d_in[2];
  const float* root   = (const float*)d_in[3];
  const float* bias   = (const float*)d_in[4];
  const int*   eidx   = (const int*)d_in[5];
  const int*   etype  = (const int*)d_in[6];
  const int E = in_sizes[6];
  const int* src = eidx;
  const int* dst = eidx + E;

  char* ws = (char*)d_ws;
  const int baseTiles = (E + TE - 1) / TE;
  const int uTmax = baseTiles + NBMAX;
  const int NBLK = (N_ + 1 + 255) / 256;
  auto al = [](size_t x) { return (x + 255) & ~(size_t)255; };

  size_t o_Wpack  = 0;
  size_t o_sd2    = al(o_Wpack + (size_t)(R_ + 1) * D_ * D_ * 2);
  size_t o_normS  = al(o_sd2 + (size_t)uTmax * TE * 8);
  size_t o_posbuf = al(o_normS + (size_t)uTmax * TE * 4);
  size_t o_cnt    = al(o_posbuf + (size_t)E * 4);
  size_t o_deg    = al(o_cnt + (size_t)SUBS * N_ * 4);
  size_t o_dstOff = al(o_deg + (size_t)N_ * 4);
  size_t o_tileRel= al(o_dstOff + (size_t)(N_ + 8) * 4);
  size_t o_small  = al(o_tileRel + (size_t)uTmax * 4);
  size_t o_y1     = al(o_small + 32768);
  size_t o_xb     = al(o_y1 + (size_t)N_ * D_ * 4);
  size_t o_xb2    = al(o_xb + (size_t)N_ * D_ * 2);
  size_t o_msg    = al(o_xb2 + (size_t)N_ * D_ * 2);
  size_t o_Wf     = o_msg;   // alias: dead after k_packW (before msg writes)

  ushort* Wpack  = (ushort*)(ws + o_Wpack);
  uint2*  sd2    = (uint2*)(ws + o_sd2);
  float*  normS  = (float*)(ws + o_normS);
  int*    posbuf = (int*)(ws + o_posbuf);
  int*    cnt    = (int*)(ws + o_cnt);
  int*    deg    = (int*)(ws + o_deg);
  int*    dstOff = (int*)(ws + o_dstOff);
  int*    tileRel= (int*)(ws + o_tileRel);
  int*    hist   = (int*)(ws + o_small);
  int*    padOff = hist + 1664;
  int*    cursor = hist + 3328;
  int*    blkSum = hist + 4992;
  int*    blkOff = hist + 5504;
  float*  y1     = (float*)(ws + o_y1);
  ushort* xb     = (ushort*)(ws + o_xb);
  ushort* xb2    = (ushort*)(ws + o_xb2);
  float*  Wf     = (float*)(ws + o_Wf);
  ushort* msg    = (ushort*)(ws + o_msg);
  ushort* rootPack = Wpack + (size_t)R_ * D_ * D_;

  // choose nch: expected chunk (with 1.5x skew margin) must fit msg capacity and ~L3
  size_t cap = (ws_size > o_msg + 16384) ? (ws_size - o_msg) : (size_t)16384;
  size_t tileBytes = (size_t)TE * D_ * 2;
  long long maxT = (long long)(cap / tileBytes);
  int nch = MAXC;
  for (int n = 1; n <= MAXC; ++n) {
    long long expT = (long long)baseTiles / n + R_ + TE;
    if (expT * 3 / 2 <= maxT && expT * (long long)tileBytes <= (136LL << 20)) { nch = n; break; }
  }
  const int NB = nch * R_;
  const int uT = baseTiles + NB;
  const int DCH = (N_ + nch - 1) / nch;
  const size_t EpadU = (size_t)uT * TE;

  (void)hipMemsetAsync(ws + o_sd2, 0xFF, EpadU * 8, stream);    // padding: src=-1, y=0xFFFFFFFF
  (void)hipMemsetAsync(ws + o_cnt, 0, (size_t)SUBS * N_ * 4, stream);
  (void)hipMemsetAsync(ws + o_small, 0, 32768, stream);

  int gH = (E + 2047) / 2048;
  k_hist<<<gH, 256, 0, stream>>>(dst, etype, E, hist, DCH, NB);
  k_scanRel<<<1, 1024, 0, stream>>>(hist, padOff, cursor, NB);
  k_scatter<<<gH, 256, 0, stream>>>(src, dst, etype, E, cursor, sd2, cnt, DCH, NB);
  k_tileRel<<<(uT + 255) / 256, 256, 0, stream>>>(padOff, tileRel, uT, NB);
  k_sub<<<(N_ + 255) / 256, 256, 0, stream>>>(cnt, deg);
  k_degPart<<<NBLK, 256, 0, stream>>>(deg, blkSum);
  k_scanBlk<<<1, 512, 0, stream>>>(blkSum, blkOff, NBLK);
  k_writeOff<<<NBLK, 256, 0, stream>>>(deg, blkOff, dstOff);
  k_buildPos<<<(int)((EpadU + 255) / 256), 256, 0, stream>>>(sd2, dstOff, cnt, posbuf, (int)EpadU);
  k_norm<<<(N_ + 3) / 4, 256, 0, stream>>>(posbuf, dstOff, tileRel, normS);

  int ntR = (N_ + TE - 1) / TE;
  int gAgg = (DCH + 3) / 4;
  k_cast<<<(N_ * D_ / 8 + 255) / 256, 256, 0, stream>>>(entity, xb, N_ * D_ / 8);
  for (int l = 0; l < 2; l++) {
    const ushort* xin = l ? xb2 : xb;
    float* yout = l ? (float*)d_out : y1;
    k_computeW<<<R_ * 64, 256, 0, stream>>>(comp + l * R_ * B_, basis + (size_t)l * B_ * D_ * D_, Wf);
    k_packW<<<R_, 256, 0, stream>>>(Wf, Wpack);
    k_packW<<<1, 256, 0, stream>>>(root + (size_t)l * D_ * D_, rootPack);
    k_root_mfma<<<(ntR + RG_ - 1) / RG_, 256, 0, stream>>>(xin, rootPack, bias + l * D_, yout, ntR);
    for (int c = 0; c < nch; c++) {
      k_edges_mfma<<<1024, 256, 0, stream>>>(xin, Wpack, sd2, normS, tileRel, padOff, msg, c);
      int dlo = c * DCH;
      int dhi = (c + 1) * DCH; if (dhi > N_) dhi = N_;
      k_agg2<<<gAgg, 256, 0, stream>>>(msg, posbuf, dstOff, padOff, yout, xb2, c, dlo, dhi, l ? 1 : 2);
    }
  }
}

// Round 18
// 993.347 us; speedup vs baseline: 1.0279x; 1.0279x over previous
//
#include <hip/hip_runtime.h>
#include <hip/hip_bf16.h>
#include <stdint.h>

#define D_ 128
#define R_ 200
#define B_ 50
#define N_ 100000
#define TE 64
#define RG_ 4
#define MAXC 8
#define NBMAX (MAXC * R_)
#define SUBS 8

typedef __attribute__((ext_vector_type(8))) short s8b;
typedef __attribute__((ext_vector_type(4))) float f32x4;
typedef __attribute__((ext_vector_type(4))) uint u32x4;

// ---------------- helpers ----------------

__device__ __forceinline__ ushort f2bf(float f) {   // RTN-even fp32 -> bf16
  uint u = __float_as_uint(f);
  return (ushort)((u + 0x7fffu + ((u >> 16) & 1u)) >> 16);
}
__device__ __forceinline__ float bf2f(ushort u) {
  return __uint_as_float(((uint)u) << 16);
}

// ---------------- bucket histogram: bucket = (dst/DCH)*R + rel ----------------

__global__ __launch_bounds__(256) void k_hist(const int* __restrict__ dst, const int* __restrict__ et,
                                              int E, int* __restrict__ hist, int DCH, int NB) {
  __shared__ int h[NBMAX];
  for (int i = threadIdx.x; i < NB; i += 256) h[i] = 0;
  __syncthreads();
  int base = blockIdx.x * 2048;
  for (int j = 0; j < 8; j++) {
    int i = base + j * 256 + threadIdx.x;
    if (i < E) {
      int key = (dst[i] / DCH) * R_ + et[i];
      atomicAdd(&h[key], 1);
    }
  }
  __syncthreads();
  for (int i = threadIdx.x; i < NB; i += 256) { int v = h[i]; if (v) atomicAdd(&hist[i], v); }
}

// parallel bucket scan with TE-padding (1 block, 1024 threads, 2 buckets/thread)
__global__ __launch_bounds__(1024) void k_scanRel(const int* __restrict__ hist,
                                                  int* __restrict__ padOff, int* __restrict__ cursor, int NB) {
  __shared__ int s[1024];
  int tid = threadIdx.x;
  int i0 = 2 * tid, i1 = 2 * tid + 1;
  int v0 = (i0 < NB) ? ((hist[i0] + TE - 1) / TE) * TE : 0;
  int v1 = (i1 < NB) ? ((hist[i1] + TE - 1) / TE) * TE : 0;
  int v = v0 + v1;
  s[tid] = v;
  __syncthreads();
  for (int off = 1; off < 1024; off <<= 1) {
    int t = (tid >= off) ? s[tid - off] : 0;
    __syncthreads();
    s[tid] += t;
    __syncthreads();
  }
  int e = s[tid] - v;
  if (i0 < NB) { padOff[i0] = e; cursor[i0] = e; }
  if (i1 < NB) { padOff[i1] = e + v0; cursor[i1] = e + v0; }
  if (tid == 1023) padOff[NB] = s[1023];
}

// bucket-sort scatter + per-(dst,sub) rank; sub-counters in SEPARATE LINES (cnt[sub*N_+d])
__global__ __launch_bounds__(256) void k_scatter(const int* __restrict__ src, const int* __restrict__ dst,
                                                 const int* __restrict__ et, int E,
                                                 int* __restrict__ cursor,
                                                 uint2* __restrict__ sd2, int* __restrict__ cnt,
                                                 int DCH, int NB) {
  __shared__ int h[NBMAX];
  __shared__ int gb[NBMAX];
  for (int i = threadIdx.x; i < NB; i += 256) h[i] = 0;
  __syncthreads();
  int base = blockIdx.x * 2048;
  int lrank[8];
#pragma unroll
  for (int j = 0; j < 8; j++) {
    int i = base + j * 256 + threadIdx.x;
    lrank[j] = 0;
    if (i < E) {
      int key = (dst[i] / DCH) * R_ + et[i];
      lrank[j] = atomicAdd(&h[key], 1);
    }
  }
  __syncthreads();
  for (int i = threadIdx.x; i < NB; i += 256) { int v = h[i]; gb[i] = v ? atomicAdd(&cursor[i], v) : 0; }
  __syncthreads();
#pragma unroll
  for (int j = 0; j < 8; j++) {
    int i = base + j * 256 + threadIdx.x;
    if (i < E) {
      int d = dst[i];
      int key = (d / DCH) * R_ + et[i];
      int pos = gb[key] + lrank[j];
      int sub = i & (SUBS - 1);
      int rank = atomicAdd(&cnt[sub * N_ + d], 1);
      uint2 sd;
      sd.x = (uint)src[i];
      sd.y = (uint)d | ((uint)sub << 17) | ((uint)rank << 20);
      sd2[pos] = sd;
    }
  }
}

__global__ __launch_bounds__(256) void k_tileRel(const int* __restrict__ padOff, int* __restrict__ tileRel,
                                                 int uT, int NB) {
  int t = blockIdx.x * 256 + threadIdx.x;
  if (t >= uT) return;
  int base = t * TE;
  if (base >= padOff[NB]) { tileRel[t] = 0; return; }
  int lo = 0, hi = NB - 1;
  while (lo < hi) { int mid = (lo + hi + 1) >> 1; if (padOff[mid] <= base) lo = mid; else hi = mid - 1; }
  tileRel[t] = lo % R_;
}

// cnt -> in-place exclusive sub-prefixes; deg[d] = total
__global__ __launch_bounds__(256) void k_sub(int* __restrict__ cnt, int* __restrict__ deg) {
  int d = blockIdx.x * 256 + threadIdx.x;
  if (d >= N_) return;
  int run = 0;
#pragma unroll
  for (int s = 0; s < SUBS; ++s) {
    int v = cnt[s * N_ + d];
    cnt[s * N_ + d] = run;
    run += v;
  }
  deg[d] = run;
}

// ---------------- dst offsets ----------------

__global__ __launch_bounds__(256) void k_degPart(const int* __restrict__ deg, int* __restrict__ blkSum) {
  __shared__ int ws_[4];
  int i = blockIdx.x * 256 + threadIdx.x;
  int v = (i < N_) ? deg[i] : 0;
#pragma unroll
  for (int off = 32; off >= 1; off >>= 1) v += __shfl_down(v, off);
  if ((threadIdx.x & 63) == 0) ws_[threadIdx.x >> 6] = v;
  __syncthreads();
  if (threadIdx.x == 0) blkSum[blockIdx.x] = ws_[0] + ws_[1] + ws_[2] + ws_[3];
}

__global__ __launch_bounds__(512) void k_scanBlk(const int* __restrict__ blkSum, int* __restrict__ blkOff, int nblk) {
  __shared__ int s[512];
  int tid = threadIdx.x;
  int v = (tid < nblk) ? blkSum[tid] : 0;
  s[tid] = v;
  __syncthreads();
  for (int off = 1; off < 512; off <<= 1) {
    int t = (tid >= off) ? s[tid - off] : 0;
    __syncthreads();
    s[tid] += t;
    __syncthreads();
  }
  if (tid < nblk) blkOff[tid] = s[tid] - v;
}

__global__ __launch_bounds__(256) void k_writeOff(const int* __restrict__ deg, const int* __restrict__ blkOff,
                                                  int* __restrict__ dstOff) {
  __shared__ int s[256];
  int i = blockIdx.x * 256 + threadIdx.x;
  int tid = threadIdx.x;
  int v = (i < N_) ? deg[i] : 0;
  s[tid] = v;
  __syncthreads();
  for (int off = 1; off < 256; off <<= 1) {
    int t = (tid >= off) ? s[tid - off] : 0;
    __syncthreads();
    s[tid] += t;
    __syncthreads();
  }
  int e = blkOff[blockIdx.x] + s[tid] - v;
  if (i < N_) dstOff[i] = e;
  else if (i == N_) dstOff[N_] = e;
}

// non-atomic posbuf build (fields unpacked from sd2.y)
__global__ __launch_bounds__(256) void k_buildPos(const uint2* __restrict__ sd2, const int* __restrict__ dstOff,
                                                  const int* __restrict__ cnt, int* __restrict__ posbuf, int pTot) {
  int p = blockIdx.x * 256 + threadIdx.x;
  if (p >= pTot) return;
  uint y = sd2[p].y;
  if (y == 0xFFFFFFFFu) return;      // padding slot
  int d = (int)(y & 0x1FFFFu);
  int sub = (int)((y >> 17) & 7u);
  int rank = (int)(y >> 20);
  posbuf[dstOff[d] + cnt[sub * N_ + d] + rank] = p;
}

// ---------------- per-edge mean-norm from dst-sorted segments ----------------

__global__ __launch_bounds__(256) void k_norm(const int* __restrict__ posbuf, const int* __restrict__ dstOff,
                                              const int* __restrict__ tileRel, float* __restrict__ normS) {
  __shared__ int rels[4][128];
  int d = blockIdx.x * 4 + (threadIdx.x >> 6);
  int sub = threadIdx.x >> 6;
  int l = threadIdx.x & 63;
  int s0 = 0, deg = 0;
  if (d < N_) { s0 = dstOff[d]; deg = dstOff[d + 1] - s0; }
  int cap = deg < 128 ? deg : 128;
  int myp[4]; int myr[4];
  for (int j = l, t = 0; j < cap; j += 64, ++t) {
    int p = posbuf[s0 + j];
    int r = tileRel[p >> 6];
    rels[sub][j] = r;
    if (t < 4) { myp[t] = p; myr[t] = r; }
  }
  __syncthreads();
  if (d >= N_) return;
  for (int j = l, t = 0; j < deg; j += 64, ++t) {
    int p, r;
    if (j < 128 && t < 4) { p = myp[t]; r = myr[t]; }
    else { p = posbuf[s0 + j]; r = tileRel[p >> 6]; }
    int cnt = 0;
    for (int k = 0; k < deg; k++) {
      int rk = (k < 128) ? rels[sub][k] : tileRel[posbuf[s0 + k] >> 6];
      cnt += (rk == r) ? 1 : 0;
    }
    normS[p] = 1.0f / (float)(cnt > 0 ? cnt : 1);
  }
}

// ---------------- W_r = sum_b comp[r,b]*basis[b]; pack to B-fragment order ----------------

__global__ __launch_bounds__(256) void k_computeW(const float* __restrict__ comp, const float* __restrict__ basis,
                                                  float* __restrict__ W) {
  __shared__ float c[B_];
  int r = blockIdx.x >> 6;
  int chunk = blockIdx.x & 63;
  if (threadIdx.x < B_) c[threadIdx.x] = comp[r * B_ + threadIdx.x];
  __syncthreads();
  int ij = chunk * 256 + threadIdx.x;
  float acc = 0.f;
#pragma unroll 10
  for (int b = 0; b < B_; b++) acc += c[b] * basis[b * (D_ * D_) + ij];
  W[r * (D_ * D_) + ij] = acc;
}

__global__ __launch_bounds__(256) void k_packW(const float* __restrict__ W, ushort* __restrict__ Wpack) {
  int r = blockIdx.x;
  const float* Wr = W + (size_t)r * (D_ * D_);
  ushort* out = Wpack + (size_t)r * (D_ * D_);
  for (int i = threadIdx.x; i < D_ * D_; i += 256) {
    int j = i & 7, l = (i >> 3) & 63, cg = (i >> 9) & 7, ks = i >> 12;
    int k = ks * 32 + (l >> 4) * 8 + j;
    int n = cg * 16 + (l & 15);
    out[i] = f2bf(Wr[k * D_ + n]);
  }
}

__global__ __launch_bounds__(256) void k_cast(const float* __restrict__ x, ushort* __restrict__ xb, int n8) {
  int i = blockIdx.x * 256 + threadIdx.x;
  if (i >= n8) return;
  const float4* xp = (const float4*)(x + (size_t)i * 8);
  float4 a = xp[0], b = xp[1];
  uint4 pk;
  pk.x = (uint)f2bf(a.x) | ((uint)f2bf(a.y) << 16);
  pk.y = (uint)f2bf(a.z) | ((uint)f2bf(a.w) << 16);
  pk.z = (uint)f2bf(b.x) | ((uint)f2bf(b.y) << 16);
  pk.w = (uint)f2bf(b.z) | ((uint)f2bf(b.w) << 16);
  *(uint4*)(xb + (size_t)i * 8) = pk;
}

// ---------------- y = x @ root + bias (MFMA, LDS-resident W, full-line stores) ----------------

__global__ __launch_bounds__(256, 2) void k_root_mfma(
    const ushort* __restrict__ xb, const ushort* __restrict__ rootPack,
    const float* __restrict__ bias, float* __restrict__ y, int nt) {
  __shared__ ushort Wl[D_ * D_];
  __shared__ float stg[4][16 * 132];
  int tstart = blockIdx.x * RG_;
  if (tstart >= nt) return;
  int tend = tstart + RG_; if (tend > nt) tend = nt;
  int w = threadIdx.x >> 6, l = threadIdx.x & 63;
  int q = l >> 4, tx = l & 15;
  int half = l >> 5, l32 = l & 31;
  float* st = stg[w];
  {
    const uint4* wp = (const uint4*)rootPack;
    uint4* wl = (uint4*)Wl;
#pragma unroll
    for (int i = 0; i < 8; ++i) wl[i * 256 + threadIdx.x] = wp[i * 256 + threadIdx.x];
  }
  float bv[8];
#pragma unroll
  for (int cg = 0; cg < 8; ++cg) bv[cg] = bias[cg * 16 + tx];
  s8b a0, a1, a2, a3;
  {
    int gr = tstart * TE + 16 * w + tx; if (gr >= N_) gr = N_ - 1;
    const s8b* xr = (const s8b*)(xb + (size_t)gr * D_);
    a0 = xr[q]; a1 = xr[4 + q]; a2 = xr[8 + q]; a3 = xr[12 + q];
  }
  __syncthreads();
  for (int tile = tstart; tile < tend; ++tile) {
    int base = tile * TE;
    s8b n0, n1, n2, n3;
    bool pre = (tile + 1 < tend);
    if (pre) {
      int gr = base + TE + 16 * w + tx; if (gr >= N_) gr = N_ - 1;
      const s8b* xn = (const s8b*)(xb + (size_t)gr * D_);
      n0 = xn[q]; n1 = xn[4 + q]; n2 = xn[8 + q]; n3 = xn[12 + q];
    }
    f32x4 acc[8];
#pragma unroll
    for (int cg = 0; cg < 8; ++cg) acc[cg] = (f32x4){0.f, 0.f, 0.f, 0.f};
#pragma unroll
    for (int cg = 0; cg < 8; ++cg) {
      s8b b0 = *(const s8b*)&Wl[((0 * 8 + cg) * 64 + l) * 8];
      s8b b1 = *(const s8b*)&Wl[((1 * 8 + cg) * 64 + l) * 8];
      s8b b2 = *(const s8b*)&Wl[((2 * 8 + cg) * 64 + l) * 8];
      s8b b3 = *(const s8b*)&Wl[((3 * 8 + cg) * 64 + l) * 8];
      acc[cg] = __builtin_amdgcn_mfma_f32_16x16x32_bf16(a0, b0, acc[cg], 0, 0, 0);
      acc[cg] = __builtin_amdgcn_mfma_f32_16x16x32_bf16(a1, b1, acc[cg], 0, 0, 0);
      acc[cg] = __builtin_amdgcn_mfma_f32_16x16x32_bf16(a2, b2, acc[cg], 0, 0, 0);
      acc[cg] = __builtin_amdgcn_mfma_f32_16x16x32_bf16(a3, b3, acc[cg], 0, 0, 0);
    }
#pragma unroll
    for (int cg = 0; cg < 8; ++cg)
#pragma unroll
      for (int r = 0; r < 4; ++r)
        st[(4 * q + r) * 132 + cg * 16 + tx] = acc[cg][r] + bv[cg];
    int grBase = base + 16 * w;
#pragma unroll
    for (int k = 0; k < 8; ++k) {
      int row = 2 * k + half;
      int gr = grBase + row;
      f32x4 v = *(const f32x4*)&st[row * 132 + l32 * 4];
      if (gr < N_) *(f32x4*)(y + (size_t)gr * D_ + l32 * 4) = v;
    }
    if (pre) { a0 = n0; a1 = n1; a2 = n2; a3 = n3; }
  }
}

// ---------------- phase A: MFMA edge messages (dst-range chunk c) ----------------

__global__ __launch_bounds__(256, 4) void k_edges_mfma(
    const ushort* __restrict__ xb, const ushort* __restrict__ Wpack,
    const uint2* __restrict__ sd2, const float* __restrict__ normS,
    const int* __restrict__ tileRel, const int* __restrict__ padOff,
    ushort* __restrict__ msg, int c) {
  __shared__ ushort Wl[D_ * D_];
  __shared__ ushort stg[4][16 * 136];
  int b0 = padOff[c * R_], b1 = padOff[(c + 1) * R_];
  int tile0 = b0 >> 6, tile1 = b1 >> 6;
  int tiles = tile1 - tile0;
  if (tiles <= 0) return;
  int G = (tiles + (int)gridDim.x - 1) / (int)gridDim.x;
  int w = threadIdx.x >> 6, l = threadIdx.x & 63;
  int q = l >> 4, tx = l & 15;
  int g = l >> 3, m = l & 7;
  ushort* st = stg[w];
  int curRel = -1;
  for (int tb = tile0 + blockIdx.x * G; tb < tile1; tb += (int)gridDim.x * G) {
    int tend = tb + G; if (tend > tile1) tend = tile1;
    s8b a0, a1, a2, a3;
    {
      int sr = (int)sd2[tb * TE + 16 * w + tx].x;
      if (sr < 0) sr = 0;
      const s8b* xr = (const s8b*)(xb + (size_t)sr * D_);
      a0 = xr[q]; a1 = xr[4 + q]; a2 = xr[8 + q]; a3 = xr[12 + q];
    }
    for (int tile = tb; tile < tend; ++tile) {
      int base = tile * TE;
      int rel = tileRel[tile];
      if (rel != curRel) {                    // block-uniform branch
        curRel = rel;
        __syncthreads();
        const uint4* wp = (const uint4*)(Wpack + (size_t)rel * (D_ * D_));
        uint4* wl = (uint4*)Wl;
#pragma unroll
        for (int i = 0; i < 8; ++i) wl[i * 256 + threadIdx.x] = wp[i * 256 + threadIdx.x];
        __syncthreads();
      }
      float nv[4];
#pragma unroll
      for (int r = 0; r < 4; ++r) nv[r] = normS[base + 16 * w + 4 * q + r];
      s8b n0, n1, n2, n3;
      bool pre = (tile + 1 < tend);
      if (pre) {
        int sr = (int)sd2[base + TE + 16 * w + tx].x;
        if (sr < 0) sr = 0;
        const s8b* xn = (const s8b*)(xb + (size_t)sr * D_);
        n0 = xn[q]; n1 = xn[4 + q]; n2 = xn[8 + q]; n3 = xn[12 + q];
      }
      f32x4 acc[8];
#pragma unroll
      for (int cg = 0; cg < 8; ++cg) acc[cg] = (f32x4){0.f, 0.f, 0.f, 0.f};
#pragma unroll
      for (int cg = 0; cg < 8; ++cg) {
        s8b b0v = *(const s8b*)&Wl[((0 * 8 + cg) * 64 + l) * 8];
        s8b b1v = *(const s8b*)&Wl[((1 * 8 + cg) * 64 + l) * 8];
        s8b b2v = *(const s8b*)&Wl[((2 * 8 + cg) * 64 + l) * 8];
        s8b b3v = *(const s8b*)&Wl[((3 * 8 + cg) * 64 + l) * 8];
        acc[cg] = __builtin_amdgcn_mfma_f32_16x16x32_bf16(a0, b0v, acc[cg], 0, 0, 0);
        acc[cg] = __builtin_amdgcn_mfma_f32_16x16x32_bf16(a1, b1v, acc[cg], 0, 0, 0);
        acc[cg] = __builtin_amdgcn_mfma_f32_16x16x32_bf16(a2, b2v, acc[cg], 0, 0, 0);
        acc[cg] = __builtin_amdgcn_mfma_f32_16x16x32_bf16(a3, b3v, acc[cg], 0, 0, 0);
      }
#pragma unroll
      for (int cg = 0; cg < 8; ++cg)
#pragma unroll
        for (int r = 0; r < 4; ++r)
          st[(4 * q + r) * 136 + cg * 16 + tx] = f2bf(acc[cg][r] * nv[r]);
      ushort* mbase = msg + (size_t)(base - b0 + 16 * w) * D_;
#pragma unroll
      for (int jj = 0; jj < 2; ++jj)
#pragma unroll
        for (int hh = 0; hh < 2; ++hh) {
          int row = 8 * jj + g;
          u32x4 v = *(const u32x4*)&st[row * 136 + hh * 64 + m * 8];
          *(u32x4*)(mbase + (size_t)row * D_ + hh * 64 + m * 8) = v;
        }
      if (pre) { a0 = n0; a1 = n1; a2 = n2; a3 = n3; }
    }
  }
}

// ---------------- phase B: wave-per-dst aggregation (single touch per dst) ----------------
// mode 1: relu, write fp32 y.  mode 2: relu, write bf16 xbOut (no y write).

__global__ __launch_bounds__(256) void k_agg2(const ushort* __restrict__ msg, const int* __restrict__ posbuf,
                                              const int* __restrict__ dstOff, const int* __restrict__ padOff,
                                              float* __restrict__ y, ushort* __restrict__ xbOut,
                                              int c, int dlo, int dhi, int mode) {
  int d = dlo + blockIdx.x * 4 + (threadIdx.x >> 6);
  if (d >= dhi) return;
  int plo = padOff[c * R_];
  int l = threadIdx.x & 63, sub = l >> 4, tx = l & 15;
  int s0 = dstOff[d], s1 = dstOff[d + 1];
  float acc[8];
#pragma unroll
  for (int i = 0; i < 8; ++i) acc[i] = 0.f;
  for (int j = s0 + sub; j < s1; j += 4) {
    int p = posbuf[j];
    u32x4 mv = *(const u32x4*)(msg + (((size_t)(p - plo)) << 7) + (tx << 3));
    acc[0] += bf2f((ushort)mv[0]); acc[1] += bf2f((ushort)(mv[0] >> 16));
    acc[2] += bf2f((ushort)mv[1]); acc[3] += bf2f((ushort)(mv[1] >> 16));
    acc[4] += bf2f((ushort)mv[2]); acc[5] += bf2f((ushort)(mv[2] >> 16));
    acc[6] += bf2f((ushort)mv[3]); acc[7] += bf2f((ushort)(mv[3] >> 16));
  }
#pragma unroll
  for (int i = 0; i < 8; ++i) {
    acc[i] += __shfl_xor(acc[i], 16);
    acc[i] += __shfl_xor(acc[i], 32);
  }
  if (sub == 0) {
    float* yp = y + (((size_t)d) << 7) + (tx << 3);
    float4 y0 = *(float4*)yp, y1 = *(float4*)(yp + 4);
    y0.x = fmaxf(y0.x + acc[0], 0.f); y0.y = fmaxf(y0.y + acc[1], 0.f);
    y0.z = fmaxf(y0.z + acc[2], 0.f); y0.w = fmaxf(y0.w + acc[3], 0.f);
    y1.x = fmaxf(y1.x + acc[4], 0.f); y1.y = fmaxf(y1.y + acc[5], 0.f);
    y1.z = fmaxf(y1.z + acc[6], 0.f); y1.w = fmaxf(y1.w + acc[7], 0.f);
    if (mode == 1) {
      *(float4*)yp = y0; *(float4*)(yp + 4) = y1;
    } else {
      uint4 pk;
      pk.x = (uint)f2bf(y0.x) | ((uint)f2bf(y0.y) << 16);
      pk.y = (uint)f2bf(y0.z) | ((uint)f2bf(y0.w) << 16);
      pk.z = (uint)f2bf(y1.x) | ((uint)f2bf(y1.y) << 16);
      pk.w = (uint)f2bf(y1.z) | ((uint)f2bf(y1.w) << 16);
      *(uint4*)(xbOut + (((size_t)d) << 7) + (tx << 3)) = pk;
    }
  }
}

// ---------------- launch ----------------

extern "C" void kernel_launch(void* const* d_in, const int* in_sizes, int n_in,
                              void* d_out, int out_size, void* d_ws, size_t ws_size,
                              hipStream_t stream) {
  const float* entity = (const float*)d_in[0];
  const float* comp   = (const float*)d_in[1];
  const float* basis  = (const float*)d_in[2];
  const float* root   = (const float*)d_in[3];
  const float* bias   = (const float*)d_in[4];
  const int*   eidx   = (const int*)d_in[5];
  const int*   etype  = (const int*)d_in[6];
  const int E = in_sizes[6];
  const int* src = eidx;
  const int* dst = eidx + E;

  char* ws = (char*)d_ws;
  const int baseTiles = (E + TE - 1) / TE;
  const int uTmax = baseTiles + NBMAX;
  const int NBLK = (N_ + 1 + 255) / 256;
  auto al = [](size_t x) { return (x + 255) & ~(size_t)255; };

  size_t o_Wpack  = 0;
  size_t o_sd2    = al(o_Wpack + (size_t)(R_ + 1) * D_ * D_ * 2);
  size_t o_normS  = al(o_sd2 + (size_t)uTmax * TE * 8);
  size_t o_posbuf = al(o_normS + (size_t)uTmax * TE * 4);
  size_t o_cnt    = al(o_posbuf + (size_t)E * 4);
  size_t o_deg    = al(o_cnt + (size_t)SUBS * N_ * 4);
  size_t o_dstOff = al(o_deg + (size_t)N_ * 4);
  size_t o_tileRel= al(o_dstOff + (size_t)(N_ + 8) * 4);
  size_t o_small  = al(o_tileRel + (size_t)uTmax * 4);
  size_t o_y1     = al(o_small + 32768);
  size_t o_xb     = al(o_y1 + (size_t)N_ * D_ * 4);
  size_t o_xb2    = al(o_xb + (size_t)N_ * D_ * 2);
  size_t o_msg    = al(o_xb2 + (size_t)N_ * D_ * 2);
  size_t o_Wf     = o_msg;   // alias: dead after k_packW (before msg writes)

  ushort* Wpack  = (ushort*)(ws + o_Wpack);
  uint2*  sd2    = (uint2*)(ws + o_sd2);
  float*  normS  = (float*)(ws + o_normS);
  int*    posbuf = (int*)(ws + o_posbuf);
  int*    cnt    = (int*)(ws + o_cnt);
  int*    deg    = (int*)(ws + o_deg);
  int*    dstOff = (int*)(ws + o_dstOff);
  int*    tileRel= (int*)(ws + o_tileRel);
  int*    hist   = (int*)(ws + o_small);
  int*    padOff = hist + 1664;
  int*    cursor = hist + 3328;
  int*    blkSum = hist + 4992;
  int*    blkOff = hist + 5504;
  float*  y1     = (float*)(ws + o_y1);
  ushort* xb     = (ushort*)(ws + o_xb);
  ushort* xb2    = (ushort*)(ws + o_xb2);
  float*  Wf     = (float*)(ws + o_Wf);
  ushort* msg    = (ushort*)(ws + o_msg);
  ushort* rootPack = Wpack + (size_t)R_ * D_ * D_;

  // choose nch: expected chunk (with 1.5x skew margin) must fit msg capacity and ~L3
  size_t cap = (ws_size > o_msg + 16384) ? (ws_size - o_msg) : (size_t)16384;
  size_t tileBytes = (size_t)TE * D_ * 2;
  long long maxT = (long long)(cap / tileBytes);
  int nch = MAXC;
  for (int n = 1; n <= MAXC; ++n) {
    long long expT = (long long)baseTiles / n + R_ + TE;
    if (expT * 3 / 2 <= maxT && expT * (long long)tileBytes <= (136LL << 20)) { nch = n; break; }
  }
  const int NB = nch * R_;
  const int uT = baseTiles + NB;
  const int DCH = (N_ + nch - 1) / nch;
  const size_t EpadU = (size_t)uT * TE;

  (void)hipMemsetAsync(ws + o_sd2, 0xFF, EpadU * 8, stream);    // padding: src=-1, y=0xFFFFFFFF
  (void)hipMemsetAsync(ws + o_cnt, 0, (size_t)SUBS * N_ * 4, stream);
  (void)hipMemsetAsync(ws + o_small, 0, 32768, stream);

  int gH = (E + 2047) / 2048;
  k_hist<<<gH, 256, 0, stream>>>(dst, etype, E, hist, DCH, NB);
  k_scanRel<<<1, 1024, 0, stream>>>(hist, padOff, cursor, NB);
  k_scatter<<<gH, 256, 0, stream>>>(src, dst, etype, E, cursor, sd2, cnt, DCH, NB);
  k_tileRel<<<(uT + 255) / 256, 256, 0, stream>>>(padOff, tileRel, uT, NB);
  k_sub<<<(N_ + 255) / 256, 256, 0, stream>>>(cnt, deg);
  k_degPart<<<NBLK, 256, 0, stream>>>(deg, blkSum);
  k_scanBlk<<<1, 512, 0, stream>>>(blkSum, blkOff, NBLK);
  k_writeOff<<<NBLK, 256, 0, stream>>>(deg, blkOff, dstOff);
  k_buildPos<<<(int)((EpadU + 255) / 256), 256, 0, stream>>>(sd2, dstOff, cnt, posbuf, (int)EpadU);
  k_norm<<<(N_ + 3) / 4, 256, 0, stream>>>(posbuf, dstOff, tileRel, normS);

  int ntR = (N_ + TE - 1) / TE;
  int gAgg = (DCH + 3) / 4;
  k_cast<<<(N_ * D_ / 8 + 255) / 256, 256, 0, stream>>>(entity, xb, N_ * D_ / 8);
  for (int l = 0; l < 2; l++) {
    const ushort* xin = l ? xb2 : xb;
    float* yout = l ? (float*)d_out : y1;
    k_computeW<<<R_ * 64, 256, 0, stream>>>(comp + l * R_ * B_, basis + (size_t)l * B_ * D_ * D_, Wf);
    k_packW<<<R_, 256, 0, stream>>>(Wf, Wpack);
    k_packW<<<1, 256, 0, stream>>>(root + (size_t)l * D_ * D_, rootPack);
    k_root_mfma<<<(ntR + RG_ - 1) / RG_, 256, 0, stream>>>(xin, rootPack, bias + l * D_, yout, ntR);
    for (int c = 0; c < nch; c++) {
      k_edges_mfma<<<1024, 256, 0, stream>>>(xin, Wpack, sd2, normS, tileRel, padOff, msg, c);
      int dlo = c * DCH;
      int dhi = (c + 1) * DCH; if (dhi > N_) dhi = N_;
      k_agg2<<<gAgg, 256, 0, stream>>>(msg, posbuf, dstOff, padOff, yout, xb2, c, dlo, dhi, l ? 1 : 2);
    }
  }
}

// Round 19
// 916.461 us; speedup vs baseline: 1.1141x; 1.0839x over previous
//
#include <hip/hip_runtime.h>
#include <hip/hip_bf16.h>
#include <stdint.h>

#define D_ 128
#define R_ 200
#define B_ 50
#define N_ 100000
#define TE 64
#define RG_ 4
#define MAXC 8
#define NBMAX (MAXC * R_)

typedef __attribute__((ext_vector_type(8))) short s8b;
typedef __attribute__((ext_vector_type(4))) float f32x4;
typedef __attribute__((ext_vector_type(4))) uint u32x4;

// ---------------- helpers ----------------

__device__ __forceinline__ ushort f2bf(float f) {   // RTN-even fp32 -> bf16
  uint u = __float_as_uint(f);
  return (ushort)((u + 0x7fffu + ((u >> 16) & 1u)) >> 16);
}
__device__ __forceinline__ float bf2f(ushort u) {
  return __uint_as_float(((uint)u) << 16);
}

// ---------------- bucket histogram: bucket = (dst/DCH)*R + rel ----------------

__global__ __launch_bounds__(256) void k_hist(const int* __restrict__ dst, const int* __restrict__ et,
                                              int E, int* __restrict__ hist, int DCH, int NB) {
  __shared__ int h[NBMAX];
  for (int i = threadIdx.x; i < NB; i += 256) h[i] = 0;
  __syncthreads();
  int base = blockIdx.x * 4096;
  for (int j = 0; j < 16; j++) {
    int i = base + j * 256 + threadIdx.x;
    if (i < E) {
      int key = (dst[i] / DCH) * R_ + et[i];
      atomicAdd(&h[key], 1);
    }
  }
  __syncthreads();
  for (int i = threadIdx.x; i < NB; i += 256) { int v = h[i]; if (v) atomicAdd(&hist[i], v); }
}

// parallel bucket scan with TE-padding (1 block, 1024 threads, 2 buckets/thread)
__global__ __launch_bounds__(1024) void k_scanRel(const int* __restrict__ hist,
                                                  int* __restrict__ padOff, int* __restrict__ cursor, int NB) {
  __shared__ int s[1024];
  int tid = threadIdx.x;
  int i0 = 2 * tid, i1 = 2 * tid + 1;
  int v0 = (i0 < NB) ? ((hist[i0] + TE - 1) / TE) * TE : 0;
  int v1 = (i1 < NB) ? ((hist[i1] + TE - 1) / TE) * TE : 0;
  int v = v0 + v1;
  s[tid] = v;
  __syncthreads();
  for (int off = 1; off < 1024; off <<= 1) {
    int t = (tid >= off) ? s[tid - off] : 0;
    __syncthreads();
    s[tid] += t;
    __syncthreads();
  }
  int e = s[tid] - v;
  if (i0 < NB) { padOff[i0] = e; cursor[i0] = e; }
  if (i1 < NB) { padOff[i1] = e + v0; cursor[i1] = e + v0; }
  if (tid == 1023) padOff[NB] = s[1023];
}

// bucket-sort scatter + per-(dst,sub) rank; record packed uint2 {src, dst|sub<<17|rank<<19}
__global__ __launch_bounds__(256) void k_scatter(const int* __restrict__ src, const int* __restrict__ dst,
                                                 const int* __restrict__ et, int E,
                                                 int* __restrict__ cursor,
                                                 uint2* __restrict__ sd2, int* __restrict__ cnt4,
                                                 int DCH, int NB) {
  __shared__ int h[NBMAX];
  __shared__ int gb[NBMAX];
  for (int i = threadIdx.x; i < NB; i += 256) h[i] = 0;
  __syncthreads();
  int base = blockIdx.x * 4096;
  int lrank[16];
#pragma unroll
  for (int j = 0; j < 16; j++) {
    int i = base + j * 256 + threadIdx.x;
    lrank[j] = 0;
    if (i < E) {
      int key = (dst[i] / DCH) * R_ + et[i];
      lrank[j] = atomicAdd(&h[key], 1);
    }
  }
  __syncthreads();
  for (int i = threadIdx.x; i < NB; i += 256) { int v = h[i]; gb[i] = v ? atomicAdd(&cursor[i], v) : 0; }
  __syncthreads();
#pragma unroll
  for (int j = 0; j < 16; j++) {
    int i = base + j * 256 + threadIdx.x;
    if (i < E) {
      int d = dst[i];
      int key = (d / DCH) * R_ + et[i];
      int pos = gb[key] + lrank[j];
      int sub = i & 3;
      int rank = atomicAdd(&cnt4[(d << 2) + sub], 1);
      uint2 sd;
      sd.x = (uint)src[i];
      sd.y = (uint)d | ((uint)sub << 17) | ((uint)rank << 19);
      sd2[pos] = sd;
    }
  }
}

__global__ __launch_bounds__(256) void k_tileRel(const int* __restrict__ padOff, int* __restrict__ tileRel,
                                                 int uT, int NB) {
  int t = blockIdx.x * 256 + threadIdx.x;
  if (t >= uT) return;
  int base = t * TE;
  if (base >= padOff[NB]) { tileRel[t] = 0; return; }
  int lo = 0, hi = NB - 1;
  while (lo < hi) { int mid = (lo + hi + 1) >> 1; if (padOff[mid] <= base) lo = mid; else hi = mid - 1; }
  tileRel[t] = lo % R_;
}

// cnt4 -> in-place exclusive sub-prefixes; deg[d] = total
__global__ __launch_bounds__(256) void k_sub(int* __restrict__ cnt4, int* __restrict__ deg) {
  int d = blockIdx.x * 256 + threadIdx.x;
  if (d >= N_) return;
  int4* c4 = (int4*)cnt4;
  int4 v = c4[d];
  int4 o;
  o.x = 0; o.y = v.x; o.z = v.x + v.y; o.w = v.x + v.y + v.z;
  deg[d] = o.w + v.w;
  c4[d] = o;
}

// ---------------- dst offsets ----------------

__global__ __launch_bounds__(256) void k_degPart(const int* __restrict__ deg, int* __restrict__ blkSum) {
  __shared__ int ws_[4];
  int i = blockIdx.x * 256 + threadIdx.x;
  int v = (i < N_) ? deg[i] : 0;
#pragma unroll
  for (int off = 32; off >= 1; off >>= 1) v += __shfl_down(v, off);
  if ((threadIdx.x & 63) == 0) ws_[threadIdx.x >> 6] = v;
  __syncthreads();
  if (threadIdx.x == 0) blkSum[blockIdx.x] = ws_[0] + ws_[1] + ws_[2] + ws_[3];
}

__global__ __launch_bounds__(512) void k_scanBlk(const int* __restrict__ blkSum, int* __restrict__ blkOff, int nblk) {
  __shared__ int s[512];
  int tid = threadIdx.x;
  int v = (tid < nblk) ? blkSum[tid] : 0;
  s[tid] = v;
  __syncthreads();
  for (int off = 1; off < 512; off <<= 1) {
    int t = (tid >= off) ? s[tid - off] : 0;
    __syncthreads();
    s[tid] += t;
    __syncthreads();
  }
  if (tid < nblk) blkOff[tid] = s[tid] - v;
}

__global__ __launch_bounds__(256) void k_writeOff(const int* __restrict__ deg, const int* __restrict__ blkOff,
                                                  int* __restrict__ dstOff) {
  __shared__ int s[256];
  int i = blockIdx.x * 256 + threadIdx.x;
  int tid = threadIdx.x;
  int v = (i < N_) ? deg[i] : 0;
  s[tid] = v;
  __syncthreads();
  for (int off = 1; off < 256; off <<= 1) {
    int t = (tid >= off) ? s[tid - off] : 0;
    __syncthreads();
    s[tid] += t;
    __syncthreads();
  }
  int e = blkOff[blockIdx.x] + s[tid] - v;
  if (i < N_) dstOff[i] = e;
  else if (i == N_) dstOff[N_] = e;
}

// non-atomic posbuf build (fields unpacked from sd2.y)
__global__ __launch_bounds__(256) void k_buildPos(const uint2* __restrict__ sd2, const int* __restrict__ dstOff,
                                                  const int* __restrict__ cnt4, int* __restrict__ posbuf, int pTot) {
  int p = blockIdx.x * 256 + threadIdx.x;
  if (p >= pTot) return;
  uint y = sd2[p].y;
  if (y == 0xFFFFFFFFu) return;      // padding slot
  int d = (int)(y & 0x1FFFFu);
  int sub = (int)((y >> 17) & 3u);
  int rank = (int)(y >> 19);
  posbuf[dstOff[d] + cnt4[(d << 2) + sub] + rank] = p;
}

// ---------------- per-edge mean-norm from dst-sorted segments ----------------

__global__ __launch_bounds__(256) void k_norm(const int* __restrict__ posbuf, const int* __restrict__ dstOff,
                                              const int* __restrict__ tileRel, float* __restrict__ normS) {
  __shared__ int rels[4][128];
  int d = blockIdx.x * 4 + (threadIdx.x >> 6);
  int sub = threadIdx.x >> 6;
  int l = threadIdx.x & 63;
  int s0 = 0, deg = 0;
  if (d < N_) { s0 = dstOff[d]; deg = dstOff[d + 1] - s0; }
  int cap = deg < 128 ? deg : 128;
  int myp[4]; int myr[4];
  for (int j = l, t = 0; j < cap; j += 64, ++t) {
    int p = posbuf[s0 + j];
    int r = tileRel[p >> 6];
    rels[sub][j] = r;
    if (t < 4) { myp[t] = p; myr[t] = r; }
  }
  __syncthreads();
  if (d >= N_) return;
  for (int j = l, t = 0; j < deg; j += 64, ++t) {
    int p, r;
    if (j < 128 && t < 4) { p = myp[t]; r = myr[t]; }
    else { p = posbuf[s0 + j]; r = tileRel[p >> 6]; }
    int cnt = 0;
    for (int k = 0; k < deg; k++) {
      int rk = (k < 128) ? rels[sub][k] : tileRel[posbuf[s0 + k] >> 6];
      cnt += (rk == r) ? 1 : 0;
    }
    normS[p] = 1.0f / (float)(cnt > 0 ? cnt : 1);
  }
}

// ---------------- W_r = sum_b comp[r,b]*basis[b]; pack to B-fragment order ----------------

__global__ __launch_bounds__(256) void k_computeW(const float* __restrict__ comp, const float* __restrict__ basis,
                                                  float* __restrict__ W) {
  __shared__ float c[B_];
  int r = blockIdx.x >> 6;
  int chunk = blockIdx.x & 63;
  if (threadIdx.x < B_) c[threadIdx.x] = comp[r * B_ + threadIdx.x];
  __syncthreads();
  int ij = chunk * 256 + threadIdx.x;
  float acc = 0.f;
#pragma unroll 10
  for (int b = 0; b < B_; b++) acc += c[b] * basis[b * (D_ * D_) + ij];
  W[r * (D_ * D_) + ij] = acc;
}

__global__ __launch_bounds__(256) void k_packW(const float* __restrict__ W, ushort* __restrict__ Wpack) {
  int r = blockIdx.x;
  const float* Wr = W + (size_t)r * (D_ * D_);
  ushort* out = Wpack + (size_t)r * (D_ * D_);
  for (int i = threadIdx.x; i < D_ * D_; i += 256) {
    int j = i & 7, l = (i >> 3) & 63, cg = (i >> 9) & 7, ks = i >> 12;
    int k = ks * 32 + (l >> 4) * 8 + j;
    int n = cg * 16 + (l & 15);
    out[i] = f2bf(Wr[k * D_ + n]);
  }
}

__global__ __launch_bounds__(256) void k_cast(const float* __restrict__ x, ushort* __restrict__ xb, int n8) {
  int i = blockIdx.x * 256 + threadIdx.x;
  if (i >= n8) return;
  const float4* xp = (const float4*)(x + (size_t)i * 8);
  float4 a = xp[0], b = xp[1];
  uint4 pk;
  pk.x = (uint)f2bf(a.x) | ((uint)f2bf(a.y) << 16);
  pk.y = (uint)f2bf(a.z) | ((uint)f2bf(a.w) << 16);
  pk.z = (uint)f2bf(b.x) | ((uint)f2bf(b.y) << 16);
  pk.w = (uint)f2bf(b.z) | ((uint)f2bf(b.w) << 16);
  *(uint4*)(xb + (size_t)i * 8) = pk;
}

// ---------------- y = x @ root + bias (MFMA, LDS-resident W, full-line stores) ----------------

__global__ __launch_bounds__(256, 2) void k_root_mfma(
    const ushort* __restrict__ xb, const ushort* __restrict__ rootPack,
    const float* __restrict__ bias, float* __restrict__ y, int nt) {
  __shared__ ushort Wl[D_ * D_];
  __shared__ float stg[4][16 * 132];
  int tstart = blockIdx.x * RG_;
  if (tstart >= nt) return;
  int tend = tstart + RG_; if (tend > nt) tend = nt;
  int w = threadIdx.x >> 6, l = threadIdx.x & 63;
  int q = l >> 4, tx = l & 15;
  int half = l >> 5, l32 = l & 31;
  float* st = stg[w];
  {
    const uint4* wp = (const uint4*)rootPack;
    uint4* wl = (uint4*)Wl;
#pragma unroll
    for (int i = 0; i < 8; ++i) wl[i * 256 + threadIdx.x] = wp[i * 256 + threadIdx.x];
  }
  float bv[8];
#pragma unroll
  for (int cg = 0; cg < 8; ++cg) bv[cg] = bias[cg * 16 + tx];
  s8b a0, a1, a2, a3;
  {
    int gr = tstart * TE + 16 * w + tx; if (gr >= N_) gr = N_ - 1;
    const s8b* xr = (const s8b*)(xb + (size_t)gr * D_);
    a0 = xr[q]; a1 = xr[4 + q]; a2 = xr[8 + q]; a3 = xr[12 + q];
  }
  __syncthreads();
  for (int tile = tstart; tile < tend; ++tile) {
    int base = tile * TE;
    s8b n0, n1, n2, n3;
    bool pre = (tile + 1 < tend);
    if (pre) {
      int gr = base + TE + 16 * w + tx; if (gr >= N_) gr = N_ - 1;
      const s8b* xn = (const s8b*)(xb + (size_t)gr * D_);
      n0 = xn[q]; n1 = xn[4 + q]; n2 = xn[8 + q]; n3 = xn[12 + q];
    }
    f32x4 acc[8];
#pragma unroll
    for (int cg = 0; cg < 8; ++cg) acc[cg] = (f32x4){0.f, 0.f, 0.f, 0.f};
#pragma unroll
    for (int cg = 0; cg < 8; ++cg) {
      s8b b0 = *(const s8b*)&Wl[((0 * 8 + cg) * 64 + l) * 8];
      s8b b1 = *(const s8b*)&Wl[((1 * 8 + cg) * 64 + l) * 8];
      s8b b2 = *(const s8b*)&Wl[((2 * 8 + cg) * 64 + l) * 8];
      s8b b3 = *(const s8b*)&Wl[((3 * 8 + cg) * 64 + l) * 8];
      acc[cg] = __builtin_amdgcn_mfma_f32_16x16x32_bf16(a0, b0, acc[cg], 0, 0, 0);
      acc[cg] = __builtin_amdgcn_mfma_f32_16x16x32_bf16(a1, b1, acc[cg], 0, 0, 0);
      acc[cg] = __builtin_amdgcn_mfma_f32_16x16x32_bf16(a2, b2, acc[cg], 0, 0, 0);
      acc[cg] = __builtin_amdgcn_mfma_f32_16x16x32_bf16(a3, b3, acc[cg], 0, 0, 0);
    }
#pragma unroll
    for (int cg = 0; cg < 8; ++cg)
#pragma unroll
      for (int r = 0; r < 4; ++r)
        st[(4 * q + r) * 132 + cg * 16 + tx] = acc[cg][r] + bv[cg];
    int grBase = base + 16 * w;
#pragma unroll
    for (int k = 0; k < 8; ++k) {
      int row = 2 * k + half;
      int gr = grBase + row;
      f32x4 v = *(const f32x4*)&st[row * 132 + l32 * 4];
      if (gr < N_) *(f32x4*)(y + (size_t)gr * D_ + l32 * 4) = v;
    }
    if (pre) { a0 = n0; a1 = n1; a2 = n2; a3 = n3; }
  }
}

// ---------------- phase A: MFMA edge messages (dst-range chunk c) ----------------

__global__ __launch_bounds__(256, 4) void k_edges_mfma(
    const ushort* __restrict__ xb, const ushort* __restrict__ Wpack,
    const uint2* __restrict__ sd2, const float* __restrict__ normS,
    const int* __restrict__ tileRel, const int* __restrict__ padOff,
    ushort* __restrict__ msg, int c) {
  __shared__ ushort Wl[D_ * D_];
  __shared__ ushort stg[4][16 * 136];
  int b0 = padOff[c * R_], b1 = padOff[(c + 1) * R_];
  int tile0 = b0 >> 6, tile1 = b1 >> 6;
  int tiles = tile1 - tile0;
  if (tiles <= 0) return;
  int G = (tiles + (int)gridDim.x - 1) / (int)gridDim.x;
  int w = threadIdx.x >> 6, l = threadIdx.x & 63;
  int q = l >> 4, tx = l & 15;
  int g = l >> 3, m = l & 7;
  ushort* st = stg[w];
  int curRel = -1;
  for (int tb = tile0 + blockIdx.x * G; tb < tile1; tb += (int)gridDim.x * G) {
    int tend = tb + G; if (tend > tile1) tend = tile1;
    s8b a0, a1, a2, a3;
    {
      int sr = (int)sd2[tb * TE + 16 * w + tx].x;
      if (sr < 0) sr = 0;
      const s8b* xr = (const s8b*)(xb + (size_t)sr * D_);
      a0 = xr[q]; a1 = xr[4 + q]; a2 = xr[8 + q]; a3 = xr[12 + q];
    }
    for (int tile = tb; tile < tend; ++tile) {
      int base = tile * TE;
      int rel = tileRel[tile];
      if (rel != curRel) {                    // block-uniform branch
        curRel = rel;
        __syncthreads();
        const uint4* wp = (const uint4*)(Wpack + (size_t)rel * (D_ * D_));
        uint4* wl = (uint4*)Wl;
#pragma unroll
        for (int i = 0; i < 8; ++i) wl[i * 256 + threadIdx.x] = wp[i * 256 + threadIdx.x];
        __syncthreads();
      }
      float nv[4];
#pragma unroll
      for (int r = 0; r < 4; ++r) nv[r] = normS[base + 16 * w + 4 * q + r];
      s8b n0, n1, n2, n3;
      bool pre = (tile + 1 < tend);
      if (pre) {
        int sr = (int)sd2[base + TE + 16 * w + tx].x;
        if (sr < 0) sr = 0;
        const s8b* xn = (const s8b*)(xb + (size_t)sr * D_);
        n0 = xn[q]; n1 = xn[4 + q]; n2 = xn[8 + q]; n3 = xn[12 + q];
      }
      f32x4 acc[8];
#pragma unroll
      for (int cg = 0; cg < 8; ++cg) acc[cg] = (f32x4){0.f, 0.f, 0.f, 0.f};
#pragma unroll
      for (int cg = 0; cg < 8; ++cg) {
        s8b b0v = *(const s8b*)&Wl[((0 * 8 + cg) * 64 + l) * 8];
        s8b b1v = *(const s8b*)&Wl[((1 * 8 + cg) * 64 + l) * 8];
        s8b b2v = *(const s8b*)&Wl[((2 * 8 + cg) * 64 + l) * 8];
        s8b b3v = *(const s8b*)&Wl[((3 * 8 + cg) * 64 + l) * 8];
        acc[cg] = __builtin_amdgcn_mfma_f32_16x16x32_bf16(a0, b0v, acc[cg], 0, 0, 0);
        acc[cg] = __builtin_amdgcn_mfma_f32_16x16x32_bf16(a1, b1v, acc[cg], 0, 0, 0);
        acc[cg] = __builtin_amdgcn_mfma_f32_16x16x32_bf16(a2, b2v, acc[cg], 0, 0, 0);
        acc[cg] = __builtin_amdgcn_mfma_f32_16x16x32_bf16(a3, b3v, acc[cg], 0, 0, 0);
      }
#pragma unroll
      for (int cg = 0; cg < 8; ++cg)
#pragma unroll
        for (int r = 0; r < 4; ++r)
          st[(4 * q + r) * 136 + cg * 16 + tx] = f2bf(acc[cg][r] * nv[r]);
      ushort* mbase = msg + (size_t)(base - b0 + 16 * w) * D_;
#pragma unroll
      for (int jj = 0; jj < 2; ++jj)
#pragma unroll
        for (int hh = 0; hh < 2; ++hh) {
          int row = 8 * jj + g;
          u32x4 v = *(const u32x4*)&st[row * 136 + hh * 64 + m * 8];
          *(u32x4*)(mbase + (size_t)row * D_ + hh * 64 + m * 8) = v;
        }
      if (pre) { a0 = n0; a1 = n1; a2 = n2; a3 = n3; }
    }
  }
}

// ---------------- phase B: wave-per-dst aggregation (single touch per dst) ----------------
// mode 1: relu, write fp32 y.  mode 2: relu, write bf16 xbOut (no y write).

__global__ __launch_bounds__(256) void k_agg2(const ushort* __restrict__ msg, const int* __restrict__ posbuf,
                                              const int* __restrict__ dstOff, const int* __restrict__ padOff,
                                              float* __restrict__ y, ushort* __restrict__ xbOut,
                                              int c, int dlo, int dhi, int mode) {
  int d = dlo + blockIdx.x * 4 + (threadIdx.x >> 6);
  if (d >= dhi) return;
  int plo = padOff[c * R_];
  int l = threadIdx.x & 63, sub = l >> 4, tx = l & 15;
  int s0 = dstOff[d], s1 = dstOff[d + 1];
  float acc[8];
#pragma unroll
  for (int i = 0; i < 8; ++i) acc[i] = 0.f;
  for (int j = s0 + sub; j < s1; j += 4) {
    int p = posbuf[j];
    u32x4 mv = *(const u32x4*)(msg + (((size_t)(p - plo)) << 7) + (tx << 3));
    acc[0] += bf2f((ushort)mv[0]); acc[1] += bf2f((ushort)(mv[0] >> 16));
    acc[2] += bf2f((ushort)mv[1]); acc[3] += bf2f((ushort)(mv[1] >> 16));
    acc[4] += bf2f((ushort)mv[2]); acc[5] += bf2f((ushort)(mv[2] >> 16));
    acc[6] += bf2f((ushort)mv[3]); acc[7] += bf2f((ushort)(mv[3] >> 16));
  }
#pragma unroll
  for (int i = 0; i < 8; ++i) {
    acc[i] += __shfl_xor(acc[i], 16);
    acc[i] += __shfl_xor(acc[i], 32);
  }
  if (sub == 0) {
    float* yp = y + (((size_t)d) << 7) + (tx << 3);
    float4 y0 = *(float4*)yp, y1 = *(float4*)(yp + 4);
    y0.x = fmaxf(y0.x + acc[0], 0.f); y0.y = fmaxf(y0.y + acc[1], 0.f);
    y0.z = fmaxf(y0.z + acc[2], 0.f); y0.w = fmaxf(y0.w + acc[3], 0.f);
    y1.x = fmaxf(y1.x + acc[4], 0.f); y1.y = fmaxf(y1.y + acc[5], 0.f);
    y1.z = fmaxf(y1.z + acc[6], 0.f); y1.w = fmaxf(y1.w + acc[7], 0.f);
    if (mode == 1) {
      *(float4*)yp = y0; *(float4*)(yp + 4) = y1;
    } else {
      uint4 pk;
      pk.x = (uint)f2bf(y0.x) | ((uint)f2bf(y0.y) << 16);
      pk.y = (uint)f2bf(y0.z) | ((uint)f2bf(y0.w) << 16);
      pk.z = (uint)f2bf(y1.x) | ((uint)f2bf(y1.y) << 16);
      pk.w = (uint)f2bf(y1.z) | ((uint)f2bf(y1.w) << 16);
      *(uint4*)(xbOut + (((size_t)d) << 7) + (tx << 3)) = pk;
    }
  }
}

// ---------------- launch ----------------

extern "C" void kernel_launch(void* const* d_in, const int* in_sizes, int n_in,
                              void* d_out, int out_size, void* d_ws, size_t ws_size,
                              hipStream_t stream) {
  const float* entity = (const float*)d_in[0];
  const float* comp   = (const float*)d_in[1];
  const float* basis  = (const float*)d_in[2];
  const float* root   = (const float*)d_in[3];
  const float* bias   = (const float*)d_in[4];
  const int*   eidx   = (const int*)d_in[5];
  const int*   etype  = (const int*)d_in[6];
  const int E = in_sizes[6];
  const int* src = eidx;
  const int* dst = eidx + E;

  char* ws = (char*)d_ws;
  const int baseTiles = (E + TE - 1) / TE;
  const int uTmax = baseTiles + NBMAX;
  const int NBLK = (N_ + 1 + 255) / 256;
  auto al = [](size_t x) { return (x + 255) & ~(size_t)255; };

  size_t o_Wpack  = 0;
  size_t o_sd2    = al(o_Wpack + (size_t)(R_ + 1) * D_ * D_ * 2);
  size_t o_normS  = al(o_sd2 + (size_t)uTmax * TE * 8);
  size_t o_posbuf = al(o_normS + (size_t)uTmax * TE * 4);
  size_t o_cnt4   = al(o_posbuf + (size_t)E * 4);
  size_t o_deg    = al(o_cnt4 + (size_t)N_ * 16);
  size_t o_dstOff = al(o_deg + (size_t)N_ * 4);
  size_t o_tileRel= al(o_dstOff + (size_t)(N_ + 8) * 4);
  size_t o_small  = al(o_tileRel + (size_t)uTmax * 4);
  size_t o_y1     = al(o_small + 32768);
  size_t o_xb     = al(o_y1 + (size_t)N_ * D_ * 4);
  size_t o_xb2    = al(o_xb + (size_t)N_ * D_ * 2);
  size_t o_msg    = al(o_xb2 + (size_t)N_ * D_ * 2);
  size_t o_Wf     = o_msg;   // alias: dead after k_packW (before msg writes)

  ushort* Wpack  = (ushort*)(ws + o_Wpack);
  uint2*  sd2    = (uint2*)(ws + o_sd2);
  float*  normS  = (float*)(ws + o_normS);
  int*    posbuf = (int*)(ws + o_posbuf);
  int*    cnt4   = (int*)(ws + o_cnt4);
  int*    deg    = (int*)(ws + o_deg);
  int*    dstOff = (int*)(ws + o_dstOff);
  int*    tileRel= (int*)(ws + o_tileRel);
  int*    hist   = (int*)(ws + o_small);
  int*    padOff = hist + 1664;
  int*    cursor = hist + 3328;
  int*    blkSum = hist + 4992;
  int*    blkOff = hist + 5504;
  float*  y1     = (float*)(ws + o_y1);
  ushort* xb     = (ushort*)(ws + o_xb);
  ushort* xb2    = (ushort*)(ws + o_xb2);
  float*  Wf     = (float*)(ws + o_Wf);
  ushort* msg    = (ushort*)(ws + o_msg);
  ushort* rootPack = Wpack + (size_t)R_ * D_ * D_;

  // choose nch: expected chunk (with 1.5x skew margin) must fit msg capacity and ~L3
  size_t cap = (ws_size > o_msg + 16384) ? (ws_size - o_msg) : (size_t)16384;
  size_t tileBytes = (size_t)TE * D_ * 2;
  long long maxT = (long long)(cap / tileBytes);
  int nch = MAXC;
  for (int n = 1; n <= MAXC; ++n) {
    long long expT = (long long)baseTiles / n + R_ + TE;
    if (expT * 3 / 2 <= maxT && expT * (long long)tileBytes <= (136LL << 20)) { nch = n; break; }
  }
  const int NB = nch * R_;
  const int uT = baseTiles + NB;
  const int DCH = (N_ + nch - 1) / nch;
  const size_t EpadU = (size_t)uT * TE;

  (void)hipMemsetAsync(ws + o_sd2, 0xFF, EpadU * 8, stream);    // padding: src=-1, y=0xFFFFFFFF
  (void)hipMemsetAsync(ws + o_cnt4, 0, (size_t)N_ * 16, stream);
  (void)hipMemsetAsync(ws + o_small, 0, 32768, stream);

  int gH = (E + 4095) / 4096;
  k_hist<<<gH, 256, 0, stream>>>(dst, etype, E, hist, DCH, NB);
  k_scanRel<<<1, 1024, 0, stream>>>(hist, padOff, cursor, NB);
  k_scatter<<<gH, 256, 0, stream>>>(src, dst, etype, E, cursor, sd2, cnt4, DCH, NB);
  k_tileRel<<<(uT + 255) / 256, 256, 0, stream>>>(padOff, tileRel, uT, NB);
  k_sub<<<(N_ + 255) / 256, 256, 0, stream>>>(cnt4, deg);
  k_degPart<<<NBLK, 256, 0, stream>>>(deg, blkSum);
  k_scanBlk<<<1, 512, 0, stream>>>(blkSum, blkOff, NBLK);
  k_writeOff<<<NBLK, 256, 0, stream>>>(deg, blkOff, dstOff);
  k_buildPos<<<(int)((EpadU + 255) / 256), 256, 0, stream>>>(sd2, dstOff, cnt4, posbuf, (int)EpadU);
  k_norm<<<(N_ + 3) / 4, 256, 0, stream>>>(posbuf, dstOff, tileRel, normS);

  int ntR = (N_ + TE - 1) / TE;
  int gAgg = (DCH + 3) / 4;
  k_cast<<<(N_ * D_ / 8 + 255) / 256, 256, 0, stream>>>(entity, xb, N_ * D_ / 8);
  for (int l = 0; l < 2; l++) {
    const ushort* xin = l ? xb2 : xb;
    float* yout = l ? (float*)d_out : y1;
    k_computeW<<<R_ * 64, 256, 0, stream>>>(comp + l * R_ * B_, basis + (size_t)l * B_ * D_ * D_, Wf);
    k_packW<<<R_, 256, 0, stream>>>(Wf, Wpack);
    k_packW<<<1, 256, 0, stream>>>(root + (size_t)l * D_ * D_, rootPack);
    k_root_mfma<<<(ntR + RG_ - 1) / RG_, 256, 0, stream>>>(xin, rootPack, bias + l * D_, yout, ntR);
    for (int c = 0; c < nch; c++) {
      k_edges_mfma<<<1024, 256, 0, stream>>>(xin, Wpack, sd2, normS, tileRel, padOff, msg, c);
      int dlo = c * DCH;
      int dhi = (c + 1) * DCH; if (dhi > N_) dhi = N_;
      k_agg2<<<gAgg, 256, 0, stream>>>(msg, posbuf, dstOff, padOff, yout, xb2, c, dlo, dhi, l ? 1 : 2);
    }
  }
}